// Round 1
// baseline (267.274 us; speedup 1.0000x reference)
//
#include <hip/hip_runtime.h>

#define BB 2
#define NN 2048
#define CC 768
#define HH 12
#define DHH 64
#define SCALE 0.125f

typedef __attribute__((ext_vector_type(4))) float f32x4;
typedef __attribute__((ext_vector_type(8))) short short8;
typedef __attribute__((ext_vector_type(4))) unsigned short u16x4;
typedef __attribute__((ext_vector_type(8))) unsigned short u16x8;

static __device__ __forceinline__ unsigned short f2bf(float f) {
    unsigned int u = __float_as_uint(f);
    u += 0x7FFFu + ((u >> 16) & 1u);   // RNE
    return (unsigned short)(u >> 16);
}

union FragU {
    u16x4 u4[2];
    u16x8 u8;
    unsigned short us[8];
    short8 s8;
};

// ---------------- f32 -> bf16 convert ----------------
__global__ void cvt_f32_bf16(const float* __restrict__ in,
                             unsigned short* __restrict__ out, int n8) {
    int i = blockIdx.x * blockDim.x + threadIdx.x;
    if (i >= n8) return;
    const f32x4* p = (const f32x4*)(in + (size_t)i * 8);
    f32x4 a = p[0], b = p[1];
    u16x8 o;
    o[0] = f2bf(a[0]); o[1] = f2bf(a[1]); o[2] = f2bf(a[2]); o[3] = f2bf(a[3]);
    o[4] = f2bf(b[0]); o[5] = f2bf(b[1]); o[6] = f2bf(b[2]); o[7] = f2bf(b[3]);
    *(u16x8*)(out + (size_t)i * 8) = o;
}

// ---------------- GEMM: C[M][N] = A[MxK] * Bt[NxK]^T ----------------
// out is bf16 (outB) or f32+bias (outF). M,N mult of 128, K mult of 32.
__launch_bounds__(256)
__global__ void gemm_bt(const unsigned short* __restrict__ A,
                        const unsigned short* __restrict__ Bt,
                        unsigned short* __restrict__ outB,
                        float* __restrict__ outF,
                        const float* __restrict__ bias,
                        int M, int N, int K) {
    __shared__ __align__(16) unsigned short As[128][40];
    __shared__ __align__(16) unsigned short Bs[128][40];
    int tid = threadIdx.x;
    int lane = tid & 63;
    int w = tid >> 6;
    int wm = w >> 1, wn = w & 1;
    int bn = blockIdx.x, bm = blockIdx.y;
    int li = lane & 15, g = lane >> 4;

    f32x4 acc[4][4] = {};
    const unsigned short* Abase = A + (size_t)(bm * 128) * K;
    const unsigned short* Bbase = Bt + (size_t)(bn * 128) * K;

    for (int k0 = 0; k0 < K; k0 += 32) {
#pragma unroll
        for (int s = 0; s < 2; ++s) {
            int q = tid + s * 256;
            int row = q >> 2, c0 = (q & 3) * 8;
            *(u16x8*)&As[row][c0] = *(const u16x8*)&Abase[(size_t)row * K + k0 + c0];
            *(u16x8*)&Bs[row][c0] = *(const u16x8*)&Bbase[(size_t)row * K + k0 + c0];
        }
        __syncthreads();
        FragU a[4], b[4];
#pragma unroll
        for (int mi = 0; mi < 4; ++mi) {
            int r = wm * 64 + mi * 16 + li;
            a[mi].u4[0] = *(const u16x4*)&As[r][g * 4];
            a[mi].u4[1] = *(const u16x4*)&As[r][g * 4 + 16];
        }
#pragma unroll
        for (int ni = 0; ni < 4; ++ni) {
            int r = wn * 64 + ni * 16 + li;
            b[ni].u4[0] = *(const u16x4*)&Bs[r][g * 4];
            b[ni].u4[1] = *(const u16x4*)&Bs[r][g * 4 + 16];
        }
#pragma unroll
        for (int mi = 0; mi < 4; ++mi)
#pragma unroll
            for (int ni = 0; ni < 4; ++ni)
                acc[mi][ni] = __builtin_amdgcn_mfma_f32_16x16x32_bf16(
                    a[mi].s8, b[ni].s8, acc[mi][ni], 0, 0, 0);
        __syncthreads();
    }

#pragma unroll
    for (int mi = 0; mi < 4; ++mi) {
#pragma unroll
        for (int ni = 0; ni < 4; ++ni) {
#pragma unroll
            for (int r = 0; r < 4; ++r) {
                int row = bm * 128 + wm * 64 + mi * 16 + g * 4 + r;
                int col = bn * 128 + wn * 64 + ni * 16 + li;
                float v = acc[mi][ni][r];
                if (outB) outB[(size_t)row * N + col] = f2bf(v);
                else      outF[(size_t)row * N + col] = v + bias[col];
            }
        }
    }
}

// ---------------- masked flash attention ----------------
// qkv: (B*N) x 2304 bf16 rows [Q(768) K(768) V(768)], per-head slices of 64.
// hout: (B*N) x 768 bf16  (already in (B,N,C) layout)
__launch_bounds__(256)
__global__ void attn_kernel(const unsigned short* __restrict__ qkv,
                            const int* __restrict__ mask,
                            unsigned short* __restrict__ hout) {
    __shared__ __align__(16) unsigned short Ks[32][72];
    __shared__ __align__(16) unsigned short Vt[64][36];
    __shared__ unsigned long long mbits[32];

    int tid = threadIdx.x;
    int lane = tid & 63;
    int w = tid >> 6;
    int li = lane & 15, g = lane >> 4;

    int qb = blockIdx.x & 31;
    int bh = blockIdx.x >> 5;
    int b = bh / HH, head = bh % HH;

    // build keep-bitmask for batch b (2048 bits)
#pragma unroll
    for (int r = 0; r < 8; ++r) {
        int j = r * 256 + w * 64 + lane;
        unsigned long long bal = __ballot(mask[b * NN + j] != 0);
        if (lane == 0) mbits[r * 4 + w] = bal;
    }

    int qrow = qb * 64 + w * 16 + li;  // softmax row owned by this lane
    size_t qoff = ((size_t)(b * NN + qrow)) * 2304 + head * DHH;
    FragU qf[2];
#pragma unroll
    for (int d0 = 0; d0 < 2; ++d0) {
        qf[d0].u4[0] = *(const u16x4*)&qkv[qoff + d0 * 32 + g * 4];
        qf[d0].u4[1] = *(const u16x4*)&qkv[qoff + d0 * 32 + g * 4 + 16];
    }
    bool rk = mask[b * NN + qrow] != 0;
    float m_st = rk ? -1e30f : 0.0f;
    float l_st = 0.0f;
    f32x4 acc[4] = {};

    int krow = tid >> 3, kc0 = (tid & 7) * 8;
    size_t kbase = ((size_t)(b * NN)) * 2304 + CC + head * DHH;
    size_t vbase = ((size_t)(b * NN)) * 2304 + 2 * CC + head * DHH;

    for (int kb = 0; kb < NN; kb += 32) {
        __syncthreads();  // protect LDS from prev iteration readers
        // stage K tile [32][64] row-major
        *(u16x8*)&Ks[krow][kc0] =
            *(const u16x8*)&qkv[kbase + (size_t)(kb + krow) * 2304 + kc0];
        // stage V tile transposed: Vt[d][j]
        u16x8 vv = *(const u16x8*)&qkv[vbase + (size_t)(kb + krow) * 2304 + kc0];
#pragma unroll
        for (int e = 0; e < 8; ++e) Vt[kc0 + e][krow] = vv[e];
        __syncthreads();

        // S^T = K * Q^T  (two 16-j tiles, K-dim 64 in two mfmas)
        f32x4 st[2];
#pragma unroll
        for (int t = 0; t < 2; ++t) {
            FragU kf0, kf1;
            kf0.u4[0] = *(const u16x4*)&Ks[t * 16 + li][g * 4];
            kf0.u4[1] = *(const u16x4*)&Ks[t * 16 + li][g * 4 + 16];
            kf1.u4[0] = *(const u16x4*)&Ks[t * 16 + li][32 + g * 4];
            kf1.u4[1] = *(const u16x4*)&Ks[t * 16 + li][32 + g * 4 + 16];
            f32x4 z = {};
            z = __builtin_amdgcn_mfma_f32_16x16x32_bf16(kf0.s8, qf[0].s8, z, 0, 0, 0);
            z = __builtin_amdgcn_mfma_f32_16x16x32_bf16(kf1.s8, qf[1].s8, z, 0, 0, 0);
            st[t] = z;
        }

        // online softmax; lane's j values: kb + 16t + 4g + r
        unsigned kbits[2];
#pragma unroll
        for (int t = 0; t < 2; ++t) {
            int j0 = kb + t * 16 + g * 4;
            kbits[t] = (unsigned)((mbits[j0 >> 6] >> (j0 & 63)) & 15ull);
        }
        float sv[2][4];
        bool pz[2][4];
        float tmax = -1e38f;
#pragma unroll
        for (int t = 0; t < 2; ++t)
#pragma unroll
            for (int r = 0; r < 4; ++r) {
                float s = st[t][r] * SCALE;
                bool ck = (kbits[t] >> r) & 1u;
                sv[t][r] = rk ? s : 0.0f;
                pz[t][r] = rk && !ck;
                float cand = rk ? (ck ? s : -1e30f) : 0.0f;
                tmax = fmaxf(tmax, cand);
            }
        tmax = fmaxf(tmax, __shfl_xor(tmax, 16));
        tmax = fmaxf(tmax, __shfl_xor(tmax, 32));
        float mnew = fmaxf(m_st, tmax);
        float alpha = __expf(m_st - mnew);
        float lsum = 0.0f;
        FragU pf;
#pragma unroll
        for (int t = 0; t < 2; ++t)
#pragma unroll
            for (int r = 0; r < 4; ++r) {
                float pv = pz[t][r] ? 0.0f : __expf(sv[t][r] - mnew);
                lsum += pv;
                pf.us[t * 4 + r] = f2bf(pv);
            }
        lsum += __shfl_xor(lsum, 16);
        lsum += __shfl_xor(lsum, 32);
        l_st = l_st * alpha + lsum;
        m_st = mnew;

        // rescale accumulator rows (O rows are 4g+r, alpha lives at lane row li)
        float ar[4];
#pragma unroll
        for (int r = 0; r < 4; ++r) ar[r] = __shfl(alpha, g * 4 + r);
#pragma unroll
        for (int dt = 0; dt < 4; ++dt)
#pragma unroll
            for (int r = 0; r < 4; ++r) acc[dt][r] *= ar[r];

        // PV: acc[dt] += P * V
#pragma unroll
        for (int dt = 0; dt < 4; ++dt) {
            FragU vf;
            vf.u4[0] = *(const u16x4*)&Vt[dt * 16 + li][g * 4];
            vf.u4[1] = *(const u16x4*)&Vt[dt * 16 + li][g * 4 + 16];
            acc[dt] = __builtin_amdgcn_mfma_f32_16x16x32_bf16(pf.s8, vf.s8, acc[dt], 0, 0, 0);
        }
    }

    float linv = 1.0f / l_st;
    float lr[4];
#pragma unroll
    for (int r = 0; r < 4; ++r) lr[r] = __shfl(linv, g * 4 + r);
#pragma unroll
    for (int dt = 0; dt < 4; ++dt)
#pragma unroll
        for (int r = 0; r < 4; ++r) {
            int orow = qb * 64 + w * 16 + g * 4 + r;
            hout[((size_t)(b * NN + orow)) * CC + head * DHH + dt * 16 + li] =
                f2bf(acc[dt][r] * lr[r]);
        }
}

extern "C" void kernel_launch(void* const* d_in, const int* in_sizes, int n_in,
                              void* d_out, int out_size, void* d_ws, size_t ws_size,
                              hipStream_t stream) {
    const float* x     = (const float*)d_in[0];
    const int*   mask  = (const int*)d_in[1];
    const float* wqkv  = (const float*)d_in[2];
    const float* wproj = (const float*)d_in[3];
    const float* bproj = (const float*)d_in[4];
    float* out = (float*)d_out;

    unsigned short* x_bf     = (unsigned short*)d_ws;          // 4096*768
    unsigned short* wqkv_bf  = x_bf + 3145728;                 // 2304*768
    unsigned short* wproj_bf = wqkv_bf + 1769472;              // 768*768
    unsigned short* qkv_bf   = wproj_bf + 589824;              // 4096*2304
    unsigned short* h_bf     = qkv_bf + 9437184;               // 4096*768
    // total: 18,087,936 ushorts = 36.2 MB

    cvt_f32_bf16<<<1536, 256, 0, stream>>>(x, x_bf, 393216);
    cvt_f32_bf16<<<864, 256, 0, stream>>>(wqkv, wqkv_bf, 221184);
    cvt_f32_bf16<<<288, 256, 0, stream>>>(wproj, wproj_bf, 73728);

    // qkv = x @ w_qkv^T   -> bf16
    gemm_bt<<<dim3(18, 32), 256, 0, stream>>>(x_bf, wqkv_bf, qkv_bf, nullptr,
                                              nullptr, 4096, 2304, 768);
    // masked flash attention -> h (B,N,C) bf16
    attn_kernel<<<768, 256, 0, stream>>>(qkv_bf, mask, h_bf);
    // out = h @ w_proj^T + b  -> f32
    gemm_bt<<<dim3(6, 32), 256, 0, stream>>>(h_bf, wproj_bf, nullptr, out,
                                             bproj, 4096, 768, 768);
}